// Round 21
// baseline (161.997 us; speedup 1.0000x reference)
//
#include <hip/hip_runtime.h>
#include <hip/hip_bf16.h>
#include <math.h>

// ---------------- problem constants ----------------
#define BN   1
#define DIMC 192
#define HI   48
#define WI   48
#define LL   2304          // HI*WI
#define EE   384
#define NN   16
#define PP   64
#define HHH  6
#define HALF 8
#define KK   4
#define BK_SEQ (BN*KK)     // 4
#define NBH  (BK_SEQ*HHH)  // 24
#define CLEN 24
#define NCHUNK 96          // CLEN*NCHUNK == LL
#define ZLD  896           // logical concat width of z|x|bc|dt GEMM (7*128)

typedef __attribute__((ext_vector_type(8))) short bf16x8;
typedef __attribute__((ext_vector_type(4))) float f32x4;

static __device__ __forceinline__ float siluf(float v) {
    return v / (1.f + expf(-v));
}
static __device__ __forceinline__ unsigned short f2bf(float f) {
    unsigned int u = __float_as_uint(f);
    u = (u + 0x7FFFu + ((u >> 16) & 1u)) >> 16;   // RNE
    return (unsigned short)u;
}
static __device__ __forceinline__ float bf2f(unsigned short u) {
    return __uint_as_float((unsigned int)u << 16);
}

// ---------------- fused prep: xseq | winT | wcatT | biascat | wmoT | woT ----------------
#define NP0 (KK*LL*DIMC)        // 1,769,472  xseq bf16
#define NP1 (768*DIMC)          //   147,456  winT bf16  (w_in^T)
#define NP2 (ZLD*EE)            //   344,064  wcatT bf16
#define NP2b 896                //            biascat fp32
#define NP3 (EE*EE)             //   147,456  wmoT bf16  (w_mout^T)
#define NP4 (256*EE)            //    98,304  woT bf16   (w_out^T, N-padded)
#define NPTOT (NP0+NP1+NP2+NP2b+NP3+NP4)

__global__ __launch_bounds__(256) void k_prep_all(const float* __restrict__ x,
                                                  const float* __restrict__ w_in,
                                                  const float* __restrict__ w_zx,
                                                  const float* __restrict__ w_bc,
                                                  const float* __restrict__ w_dt,
                                                  const float* __restrict__ b_bc,
                                                  const float* __restrict__ dt_bias,
                                                  const float* __restrict__ w_mout,
                                                  const float* __restrict__ w_out,
                                                  unsigned short* __restrict__ xseq,
                                                  unsigned short* __restrict__ winT,
                                                  unsigned short* __restrict__ wcatT,
                                                  float* __restrict__ biascat,
                                                  unsigned short* __restrict__ wmoT,
                                                  unsigned short* __restrict__ woT) {
    int idx = blockIdx.x * 256 + threadIdx.x;
    if (idx < NP0) {
        int d = idx % DIMC;
        int l = (idx / DIMC) % LL;
        int k = idx / (DIMC * LL);
        int dim = l / 12;
        int pos = (l % 12) * DIMC + d;
        int src;
        if (k == 0)      src = pos;
        else if (k == 1) src = (pos % 48) * 48 + pos / 48;
        else if (k == 2) src = 2303 - pos;
        else { int p2 = 2303 - pos; src = (p2 % 48) * 48 + p2 / 48; }
        xseq[idx] = f2bf(x[dim * LL + src]);
        return;
    }
    idx -= NP0;
    if (idx < NP1) {            // winT[n*192+k] = w_in[k*768+n]
        int r = idx % DIMC;
        int c = idx / DIMC;
        winT[idx] = f2bf(w_in[(size_t)r * 768 + c]);
        return;
    }
    idx -= NP1;
    if (idx < NP2) {            // wcatT[n*384+k] = [w_zx|w_bc|w_dt][k][n]
        int n = idx / EE, k = idx % EE;
        float v = 0.f;
        if (n < 768)      v = w_zx[(size_t)k * 768 + n];
        else if (n < 800) v = w_bc[(size_t)k * 32 + (n - 768)];
        else if (n < 806) v = w_dt[(size_t)k * 6 + (n - 800)];
        wcatT[idx] = f2bf(v);
        return;
    }
    idx -= NP2;
    if (idx < NP2b) {           // biascat fp32
        float v = 0.f;
        if (idx >= 768 && idx < 800) v = b_bc[idx - 768];
        else if (idx >= 800 && idx < 806) v = dt_bias[idx - 800];
        biascat[idx] = v;
        return;
    }
    idx -= NP2b;
    if (idx < NP3) {            // wmoT[n*384+k] = w_mout[k*384+n]
        int r = idx % EE;
        int c = idx / EE;
        wmoT[idx] = f2bf(w_mout[(size_t)r * EE + c]);
        return;
    }
    idx -= NP3;
    if (idx < NP4) {            // woT[d*384+e] = d<192 ? w_out[e*192+d] : 0
        int d = idx / EE, e = idx % EE;
        woT[idx] = (d < DIMC) ? f2bf(w_out[(size_t)e * DIMC + d]) : (unsigned short)0;
    }
}

// ---------------- bf16 MFMA GEMM: out = A * BT^T ----------------
// Tile 64(M) x 128(N), BK=32, 4 waves, single barrier/iter, LDS dbuf.
// EPI=0: C fp32 (+bias), ld ldc.                      [out GEMM]
// EPI=1: col<384 -> X bf16 silu; col>=384 -> Y bf16 silu (gate).   [proj]
// EPI=2: col<384 -> X bf16 silu (zsil); 384<=col<768 -> Y bf16 (xh);
//        col>=768 -> C fp32 ld 128 at col-768, + bias[col].        [zx]
// EPI=3: X bf16, ld ldc (no bias).                    [mout]
template <int EPI>
__global__ __launch_bounds__(256) void gemm_bf16(const unsigned short* __restrict__ A,
                                                 const unsigned short* __restrict__ BT,
                                                 const float* __restrict__ bias,
                                                 float* __restrict__ C,
                                                 unsigned short* __restrict__ X,
                                                 unsigned short* __restrict__ Y,
                                                 int K, int lda, int ldbt, int ldc) {
    __shared__ __align__(16) unsigned short As[2][64][40];
    __shared__ __align__(16) unsigned short Bs[2][128][40];
    int bm = blockIdx.y * 64, bn = blockIdx.x * 128;
    int tid = threadIdx.x;
    int lane = tid & 63, wave = tid >> 6;
    int wn = wave * 32;
    f32x4 acc[4][2];
#pragma unroll
    for (int f = 0; f < 4; f++)
#pragma unroll
        for (int g = 0; g < 2; g++) acc[f][g] = (f32x4){0.f, 0.f, 0.f, 0.f};

    int fr = lane & 15;
    int kl = (lane >> 4) * 8;

    int sr = tid >> 2;
    int sq = (tid & 3) * 8;
    const unsigned short* aptr  = A + (size_t)(bm + sr) * lda + sq;
    const unsigned short* bptr0 = BT + (size_t)(bn + sr) * ldbt + sq;
    const unsigned short* bptr1 = BT + (size_t)(bn + sr + 64) * ldbt + sq;

    uint4 pa  = *(const uint4*)aptr;
    uint4 pb0 = *(const uint4*)bptr0;
    uint4 pb1 = *(const uint4*)bptr1;
    *(uint4*)&As[0][sr][sq]      = pa;
    *(uint4*)&Bs[0][sr][sq]      = pb0;
    *(uint4*)&Bs[0][sr + 64][sq] = pb1;
    if (K > 32) {
        pa  = *(const uint4*)(aptr + 32);
        pb0 = *(const uint4*)(bptr0 + 32);
        pb1 = *(const uint4*)(bptr1 + 32);
    }
    __syncthreads();

    for (int k0 = 0; k0 < K; k0 += 32) {
        int cur = (k0 >> 5) & 1;
        bf16x8 af[4], bg[2];
#pragma unroll
        for (int f = 0; f < 4; f++) af[f] = *(const bf16x8*)&As[cur][f * 16 + fr][kl];
#pragma unroll
        for (int g = 0; g < 2; g++) bg[g] = *(const bf16x8*)&Bs[cur][wn + g * 16 + fr][kl];
        if (k0 + 32 < K) {
            *(uint4*)&As[cur ^ 1][sr][sq]      = pa;
            *(uint4*)&Bs[cur ^ 1][sr][sq]      = pb0;
            *(uint4*)&Bs[cur ^ 1][sr + 64][sq] = pb1;
        }
        if (k0 + 64 < K) {
            pa  = *(const uint4*)(aptr + k0 + 64);
            pb0 = *(const uint4*)(bptr0 + k0 + 64);
            pb1 = *(const uint4*)(bptr1 + k0 + 64);
        }
        __syncthreads();
#pragma unroll
        for (int f = 0; f < 4; f++)
#pragma unroll
            for (int g = 0; g < 2; g++)
                acc[f][g] = __builtin_amdgcn_mfma_f32_16x16x32_bf16(af[f], bg[g], acc[f][g], 0, 0, 0);
    }
    int cc = lane & 15, crb = (lane >> 4) * 4;
#pragma unroll
    for (int f = 0; f < 4; f++)
#pragma unroll
        for (int g = 0; g < 2; g++) {
            int col = bn + wn + g * 16 + cc;
            int rowb = bm + f * 16 + crb;
            if (EPI == 0) {
                float bv = bias ? bias[col] : 0.f;
#pragma unroll
                for (int i = 0; i < 4; i++)
                    C[(size_t)(rowb + i) * ldc + col] = acc[f][g][i] + bv;
            } else if (EPI == 1) {
                if (col < 384) {
#pragma unroll
                    for (int i = 0; i < 4; i++)
                        X[(size_t)(rowb + i) * 384 + col] = f2bf(siluf(acc[f][g][i]));
                } else {
#pragma unroll
                    for (int i = 0; i < 4; i++)
                        Y[(size_t)(rowb + i) * 384 + col - 384] = f2bf(siluf(acc[f][g][i]));
                }
            } else if (EPI == 2) {
                if (col < 384) {
#pragma unroll
                    for (int i = 0; i < 4; i++)
                        X[(size_t)(rowb + i) * 384 + col] = f2bf(siluf(acc[f][g][i]));
                } else if (col < 768) {
#pragma unroll
                    for (int i = 0; i < 4; i++)
                        Y[(size_t)(rowb + i) * 384 + col - 384] = f2bf(acc[f][g][i]);
                } else {
                    float bv = bias[col];
#pragma unroll
                    for (int i = 0; i < 4; i++)
                        C[(size_t)(rowb + i) * 128 + col - 768] = acc[f][g][i] + bv;
                }
            } else {  // EPI == 3
#pragma unroll
                for (int i = 0; i < 4; i++)
                    X[(size_t)(rowb + i) * ldc + col] = f2bf(acc[f][g][i]);
            }
        }
}

// ------- out GEMM with fused 4-direction merge in A-staging -------
// outT[l][d] = sum_e merge(l,e) * woT[d][e],  merge computed inline.
// Tile 64(M=l) x 128(N=d), K=EE=384, same schedule as gemm_bf16.
__global__ __launch_bounds__(256) void gemm_out_merge(const unsigned short* __restrict__ mresb,
                                                      const unsigned short* __restrict__ gsil,
                                                      const unsigned short* __restrict__ woT,
                                                      float* __restrict__ C) {
    __shared__ __align__(16) unsigned short As[2][64][40];
    __shared__ __align__(16) unsigned short Bs[2][128][40];
    const int K = EE;
    int bm = blockIdx.y * 64, bn = blockIdx.x * 128;
    int tid = threadIdx.x;
    int lane = tid & 63, wave = tid >> 6;
    int wn = wave * 32;
    f32x4 acc[4][2];
#pragma unroll
    for (int f = 0; f < 4; f++)
#pragma unroll
        for (int g = 0; g < 2; g++) acc[f][g] = (f32x4){0.f, 0.f, 0.f, 0.f};

    int fr = lane & 15;
    int kl = (lane >> 4) * 8;

    int sr = tid >> 2;
    int sq = (tid & 3) * 8;
    // merge row indices for l = bm + sr
    int l = bm + sr;
    int l1 = (l % 48) * 48 + l / 48;
    int r0 = 0 * LL + l;
    int r1 = 1 * LL + l1;
    int r2 = 2 * LL + (2303 - l);
    int r3 = 3 * LL + (2303 - l1);

    const unsigned short* bptr0 = woT + (size_t)(bn + sr) * EE + sq;
    const unsigned short* bptr1 = woT + (size_t)(bn + sr + 64) * EE + sq;

    // inline merge of 8 elements at e0 for row l
    auto mload = [&](int e0) -> uint4 {
        float accm[8];
#pragma unroll
        for (int j = 0; j < 8; j++) accm[j] = 0.f;
        int rows[4] = {r0, r1, r2, r3};
#pragma unroll
        for (int k = 0; k < 4; k++) {
            uint4 mv = *(const uint4*)&mresb[(size_t)rows[k] * EE + e0];
            uint4 gv = *(const uint4*)&gsil[(size_t)rows[k] * EE + e0];
            const unsigned short* mp = (const unsigned short*)&mv;
            const unsigned short* gp = (const unsigned short*)&gv;
#pragma unroll
            for (int j = 0; j < 8; j++) accm[j] += bf2f(mp[j]) * bf2f(gp[j]);
        }
        unsigned short o[8];
#pragma unroll
        for (int j = 0; j < 8; j++) o[j] = f2bf(accm[j]);
        return *(const uint4*)o;
    };

    uint4 pa  = mload(sq);
    uint4 pb0 = *(const uint4*)bptr0;
    uint4 pb1 = *(const uint4*)bptr1;
    *(uint4*)&As[0][sr][sq]      = pa;
    *(uint4*)&Bs[0][sr][sq]      = pb0;
    *(uint4*)&Bs[0][sr + 64][sq] = pb1;
    pa  = mload(sq + 32);
    pb0 = *(const uint4*)(bptr0 + 32);
    pb1 = *(const uint4*)(bptr1 + 32);
    __syncthreads();

    for (int k0 = 0; k0 < K; k0 += 32) {
        int cur = (k0 >> 5) & 1;
        bf16x8 af[4], bg[2];
#pragma unroll
        for (int f = 0; f < 4; f++) af[f] = *(const bf16x8*)&As[cur][f * 16 + fr][kl];
#pragma unroll
        for (int g = 0; g < 2; g++) bg[g] = *(const bf16x8*)&Bs[cur][wn + g * 16 + fr][kl];
        if (k0 + 32 < K) {
            *(uint4*)&As[cur ^ 1][sr][sq]      = pa;
            *(uint4*)&Bs[cur ^ 1][sr][sq]      = pb0;
            *(uint4*)&Bs[cur ^ 1][sr + 64][sq] = pb1;
        }
        if (k0 + 64 < K) {
            pa  = mload(sq + k0 + 64);
            pb0 = *(const uint4*)(bptr0 + k0 + 64);
            pb1 = *(const uint4*)(bptr1 + k0 + 64);
        }
        __syncthreads();
#pragma unroll
        for (int f = 0; f < 4; f++)
#pragma unroll
            for (int g = 0; g < 2; g++)
                acc[f][g] = __builtin_amdgcn_mfma_f32_16x16x32_bf16(af[f], bg[g], acc[f][g], 0, 0, 0);
    }
    int cc = lane & 15, crb = (lane >> 4) * 4;
#pragma unroll
    for (int f = 0; f < 4; f++)
#pragma unroll
        for (int g = 0; g < 2; g++) {
            int col = bn + wn + g * 16 + cc;
            int rowb = bm + f * 16 + crb;
#pragma unroll
            for (int i = 0; i < 4; i++)
                C[(size_t)(rowb + i) * 256 + col] = acc[f][g][i];
        }
}

// ---------------- softplus/r + cumsum of dt over l, per (bh); reads bcdt ----------------
__global__ __launch_bounds__(256) void k_dtcum(const float* __restrict__ bcdt,
                                               const float* __restrict__ A_log,
                                               float* __restrict__ dtv,
                                               float* __restrict__ rrv,
                                               float* __restrict__ cum) {
    int bh = blockIdx.x;
    int tid = threadIdx.x;
    int b = bh / HHH, h = bh % HHH;
    float aexp = expf(A_log[h]);
    const int PER = 9;                    // 256*9 = 2304
    int base = tid * PER;
    float p[PER];
    float s = 0.f;
#pragma unroll
    for (int j = 0; j < PER; j++) {
        int l = base + j;
        float xv = bcdt[((size_t)b * LL + l) * 128 + 32 + h];
        float sp = fmaxf(xv, 0.f) + log1pf(expf(-fabsf(xv)));   // softplus
        dtv[(size_t)bh * LL + l] = sp;
        rrv[(size_t)bh * LL + l] = expf(-sp * aexp);
        s += sp; p[j] = s;
    }
    __shared__ float sh[256];
    sh[tid] = s;
    __syncthreads();
    for (int off = 1; off < 256; off <<= 1) {
        float t = (tid >= off) ? sh[tid - off] : 0.f;
        __syncthreads();
        sh[tid] += t;
        __syncthreads();
    }
    float excl = sh[tid] - s;
#pragma unroll
    for (int j = 0; j < PER; j++) cum[(size_t)bh * LL + base + j] = excl + p[j];
}

// ---- RMS-normalize B/C and rotate -> btct; one thread per (b,h,l); float4 I/O ----
__global__ __launch_bounds__(256) void k_rot(const float* __restrict__ bcdt,
                                             const float* __restrict__ cum,
                                             const float* __restrict__ theta,
                                             float* __restrict__ btct) {
    int idx = blockIdx.x * 256 + threadIdx.x;
    if (idx >= NBH * LL) return;
    int bh = idx / LL, l = idx % LL;
    int b = bh / HHH, h = bh % HHH;
    const float4* bcrow = (const float4*)(bcdt + ((size_t)b * LL + l) * 128);
    float Bm[16], Cm[16];
#pragma unroll
    for (int q = 0; q < 4; q++) {
        *(float4*)&Bm[q * 4] = bcrow[q];
        *(float4*)&Cm[q * 4] = bcrow[4 + q];
    }
    float sb = 0.f, sc = 0.f;
#pragma unroll
    for (int j = 0; j < 16; j++) { sb += Bm[j] * Bm[j]; sc += Cm[j] * Cm[j]; }
    float rb = rsqrtf(sb * (1.f / 16.f) + 1e-6f);
    float rc = rsqrtf(sc * (1.f / 16.f) + 1e-6f);
    float cd = cum[(size_t)bh * LL + l];
    float out32[32];
#pragma unroll
    for (int j = 0; j < 8; j++) {
        float ang = cd * theta[h * 8 + j];
        float cc = cosf(ang), ss = sinf(ang);
        float b0 = Bm[2 * j] * rb, b1 = Bm[2 * j + 1] * rb;
        out32[2 * j]     = b0 * cc + b1 * ss;
        out32[2 * j + 1] = -b0 * ss + b1 * cc;
        float c0 = Cm[2 * j] * rc, c1 = Cm[2 * j + 1] * rc;
        out32[16 + 2 * j]     = c0 * cc + c1 * ss;
        out32[16 + 2 * j + 1] = -c0 * ss + c1 * cc;
    }
    float4* outp = (float4*)(btct + ((size_t)bh * LL + l) * 32);
#pragma unroll
    for (int q = 0; q < 8; q++) outp[q] = *(const float4*)&out32[q * 4];
}

// ---------------- scan phases A (MODE 0) and C (MODE 1), two-pass ----------------
template <int MODE>
__global__ __launch_bounds__(64) void k_scan_phase(const float* __restrict__ btct,
                                                   const float* __restrict__ rrv,
                                                   const float* __restrict__ dtv,
                                                   const unsigned short* __restrict__ xhb,
                                                   const float* __restrict__ h0,
                                                   float* __restrict__ Hc,
                                                   float* __restrict__ Rc,
                                                   unsigned short* __restrict__ yDb,
                                                   const float* __restrict__ Dsk) {
    int chunk = blockIdx.x;
    int bh = blockIdx.y;
    int lane = threadIdx.x;
    int b = bh / HHH, h = bh % HHH;
    int t0 = chunk * CLEN;

    __shared__ float sbt[(CLEN + 1) * 32];
    __shared__ float srd[2 * CLEN];

    const float* bt_row = btct + (size_t)bh * LL * 32;
    for (int i = lane; i < (CLEN + 1) * 8; i += 64) {
        int t = t0 - 1 + (i >> 3);
        float4 v = make_float4(0.f, 0.f, 0.f, 0.f);
        if (t >= 0)
            v = ((const float4*)(bt_row + (size_t)t * 32))[i & 7];
        ((float4*)sbt)[i] = v;
    }
    if (lane < CLEN) {
        srd[lane] = rrv[(size_t)bh * LL + t0 + lane];
        srd[CLEN + lane] = 0.5f * dtv[(size_t)bh * LL + t0 + lane];
    }

    const unsigned short* xcol = xhb + (size_t)b * LL * EE + h * PP + lane;
    float xr[CLEN];
#pragma unroll
    for (int j = 0; j < CLEN; j++) xr[j] = bf2f(xcol[(size_t)(t0 + j) * EE]);
    float xprev = (t0 > 0) ? bf2f(xcol[(size_t)(t0 - 1) * EE]) : 0.f;

    float hreg[16];
    if (MODE == 0) {
#pragma unroll
        for (int n = 0; n < 16; n++) hreg[n] = 0.f;
    } else {
        const float* hp = h0 + ((size_t)(chunk * NBH + bh) * 16) * PP + lane;
#pragma unroll
        for (int n = 0; n < 16; n++) hreg[n] = hp[n * PP];
    }
    float dsk = (MODE == 1) ? Dsk[h] : 0.f;
    __syncthreads();

    float Btp[16];
#pragma unroll
    for (int n = 0; n < 16; n++) Btp[n] = sbt[n];
    float Rprod = 1.f;

#pragma unroll
    for (int j = 0; j < CLEN; j++) {
        float r = srd[j];
        float dhalf = srd[CLEN + j];
        float xcur = xr[j];
        const float* bb = sbt + (j + 1) * 32;
        float a = dhalf * xcur;
        float ap = dhalf * r * xprev;
        float y = 0.f;
#pragma unroll
        for (int n = 0; n < 16; n++) {
            float Btn = bb[n];
            hreg[n] = r * hreg[n] + a * Btn + ap * Btp[n];
            Btp[n] = Btn;
            if (MODE) y += bb[16 + n] * hreg[n];
        }
        xprev = xcur;
        if (MODE) {
            yDb[((size_t)b * LL + t0 + j) * EE + h * PP + lane] = f2bf(y + dsk * xcur);
        } else {
            Rprod *= r;
        }
    }
    if (MODE == 0) {
        float* Hp = Hc + ((size_t)(chunk * NBH + bh) * 16) * PP + lane;
#pragma unroll
        for (int n = 0; n < 16; n++) Hp[n * PP] = hreg[n];
        if (lane == 0) Rc[chunk * NBH + bh] = Rprod;
    }
}

// ---------------- scan phase B: combine chunk summaries ----------------
__global__ __launch_bounds__(64) void k_scan_combine(const float* __restrict__ Hc,
                                                     const float* __restrict__ Rc,
                                                     float* __restrict__ h0) {
    int bh = blockIdx.x;
    int lane = threadIdx.x;
    float s[16];
#pragma unroll
    for (int n = 0; n < 16; n++) s[n] = 0.f;
    float* out0 = h0 + ((size_t)(0 * NBH + bh) * 16) * PP + lane;
#pragma unroll
    for (int n = 0; n < 16; n++) out0[n * PP] = 0.f;
    for (int c = 0; c < NCHUNK - 1; ++c) {
        float R = Rc[c * NBH + bh];
        const float* Hp = Hc + ((size_t)(c * NBH + bh) * 16) * PP + lane;
        float* op = h0 + ((size_t)((c + 1) * NBH + bh) * 16) * PP + lane;
#pragma unroll
        for (int n = 0; n < 16; n++) {
            s[n] = R * s[n] + Hp[n * PP];
            op[n * PP] = s[n];
        }
    }
}

// ---- g = rms(y * zsil) * rms_w; 4 rows/block, 1 wave/row, uint4 (8 bf16)/lane ----
__global__ __launch_bounds__(256) void k_gmul(const unsigned short* __restrict__ yDb,
                                              const unsigned short* __restrict__ zsil,
                                              const float* __restrict__ rms_w,
                                              unsigned short* __restrict__ g) {
    int wid = threadIdx.x >> 6, lane = threadIdx.x & 63;
    int row = blockIdx.x * 4 + wid;
    float v[8];
    float ss = 0.f;
    if (lane < 48) {
        uint4 yv = *(const uint4*)&yDb[(size_t)row * EE + lane * 8];
        uint4 zv = *(const uint4*)&zsil[(size_t)row * EE + lane * 8];
        const unsigned short* yp = (const unsigned short*)&yv;
        const unsigned short* zp = (const unsigned short*)&zv;
#pragma unroll
        for (int j = 0; j < 8; j++) {
            v[j] = bf2f(yp[j]) * bf2f(zp[j]);
            ss += v[j] * v[j];
        }
    }
#pragma unroll
    for (int off = 1; off < 64; off <<= 1) ss += __shfl_xor(ss, off);
    float scale = rsqrtf(ss * (1.f / (float)EE) + 1e-6f);
    if (lane < 48) {
        unsigned short o[8];
#pragma unroll
        for (int j = 0; j < 8; j++)
            o[j] = f2bf(v[j] * scale * rms_w[lane * 8 + j]);
        *(uint4*)&g[(size_t)row * EE + lane * 8] = *(const uint4*)o;
    }
}

// ---------------- LayerNorm over channels + residual ----------------
__global__ __launch_bounds__(64) void k_ln(const float* __restrict__ outT,
                                           const float* __restrict__ x,
                                           const float* __restrict__ ln_g,
                                           const float* __restrict__ ln_b,
                                           const float* __restrict__ res_scale,
                                           float* __restrict__ outF) {
    int l = blockIdx.x;
    int lane = threadIdx.x;
    float v[3];
    float s = 0.f;
#pragma unroll
    for (int j = 0; j < 3; j++) {
        int d = lane * 3 + j;
        v[j] = outT[(size_t)l * 256 + d];
        s += v[j];
    }
#pragma unroll
    for (int off = 1; off < 64; off <<= 1) s += __shfl_xor(s, off);
    float mu = s * (1.f / (float)DIMC);
    float sq = 0.f;
#pragma unroll
    for (int j = 0; j < 3; j++) { float dlt = v[j] - mu; sq += dlt * dlt; }
#pragma unroll
    for (int off = 1; off < 64; off <<= 1) sq += __shfl_xor(sq, off);
    float rstd = rsqrtf(sq * (1.f / (float)DIMC) + 1e-5f);
    float rs = res_scale[0];
#pragma unroll
    for (int j = 0; j < 3; j++) {
        int d = lane * 3 + j;
        outF[(size_t)d * LL + l] =
            x[(size_t)d * LL + l] + rs * ((v[j] - mu) * rstd * ln_g[d] + ln_b[d]);
    }
}

// ---------------- host launcher ----------------
extern "C" void kernel_launch(void* const* d_in, const int* in_sizes, int n_in,
                              void* d_out, int out_size, void* d_ws, size_t ws_size,
                              hipStream_t stream) {
    const float* x        = (const float*)d_in[0];
    const float* w_in     = (const float*)d_in[1];
    const float* w_zx     = (const float*)d_in[2];
    const float* w_bc     = (const float*)d_in[3];
    const float* b_bc     = (const float*)d_in[4];
    const float* w_dt     = (const float*)d_in[5];
    const float* dt_bias  = (const float*)d_in[6];
    const float* A_log    = (const float*)d_in[7];
    const float* theta    = (const float*)d_in[8];
    const float* D_skip   = (const float*)d_in[9];
    const float* rms_w    = (const float*)d_in[10];
    const float* w_mout   = (const float*)d_in[11];
    const float* w_out    = (const float*)d_in[12];
    const float* ln_g     = (const float*)d_in[13];
    const float* ln_b     = (const float*)d_in[14];
    const float* res_scale= (const float*)d_in[15];
    float* outF = (float*)d_out;
    float* ws = (float*)d_ws;

    size_t o = 0;
    auto alloc = [&](size_t n) { size_t r = o; o += (n + 127) & ~(size_t)127; return r; };
    size_t xseqb_o = alloc((size_t)9216 * DIMC / 2);   // bf16
    size_t winT_o  = alloc((size_t)768 * DIMC / 2);    // bf16
    size_t wcatT_o = alloc((size_t)ZLD * EE / 2);      // bf16
    size_t wmoT_o  = alloc((size_t)384 * 384 / 2);     // bf16
    size_t woT_o   = alloc((size_t)256 * EE / 2);      // bf16
    size_t bcat_o  = alloc(ZLD);
    size_t xact_o  = alloc((size_t)9216 * EE / 2);     // bf16; reused as g_bf
    size_t gsil_o  = alloc((size_t)9216 * EE / 2);     // bf16 silu(gate)
    size_t zsil_o  = alloc((size_t)9216 * EE / 2);     // bf16 silu(z); reused as mresb
    size_t xhb_o   = alloc((size_t)9216 * EE / 2);     // bf16 xi
    size_t bcdt_o  = alloc((size_t)9216 * 128);        // fp32 bc|dt
    size_t dtv_o   = alloc((size_t)NBH * LL);
    size_t rrv_o   = alloc((size_t)NBH * LL);
    size_t cum_o   = alloc((size_t)NBH * LL);
    size_t btct_o  = alloc((size_t)NBH * LL * 32);
    size_t Hc_o    = alloc((size_t)NCHUNK * NBH * 16 * PP);
    size_t Rc_o    = alloc((size_t)NCHUNK * NBH);
    size_t h0_o    = alloc((size_t)NCHUNK * NBH * 16 * PP);
    size_t yDb_o   = alloc((size_t)9216 * EE / 2);     // bf16
    size_t outT_o  = alloc((size_t)LL * 256);

    unsigned short* xseqb = (unsigned short*)(ws + xseqb_o);
    unsigned short* winT  = (unsigned short*)(ws + winT_o);
    unsigned short* wcatT = (unsigned short*)(ws + wcatT_o);
    unsigned short* wmoT  = (unsigned short*)(ws + wmoT_o);
    unsigned short* woT   = (unsigned short*)(ws + woT_o);
    float* bcat = ws + bcat_o;
    unsigned short* xact = (unsigned short*)(ws + xact_o);
    unsigned short* gsil = (unsigned short*)(ws + gsil_o);
    unsigned short* zsil = (unsigned short*)(ws + zsil_o);
    unsigned short* xhb  = (unsigned short*)(ws + xhb_o);
    float* bcdt = ws + bcdt_o;
    float* dtv  = ws + dtv_o;
    float* rrv  = ws + rrv_o;
    float* cum  = ws + cum_o;
    float* btct = ws + btct_o;
    float* Hc   = ws + Hc_o;
    float* Rc   = ws + Rc_o;
    float* h0   = ws + h0_o;
    unsigned short* yDb = (unsigned short*)(ws + yDb_o);
    float* outT = ws + outT_o;
    unsigned short* g_bf  = xact;   // alias (xact dead after zx GEMM)
    unsigned short* mresb = zsil;   // alias (zsil dead after k_gmul)

    // 1. fused prep
    k_prep_all<<<(NPTOT + 255) / 256, 256, 0, stream>>>(
        x, w_in, w_zx, w_bc, w_dt, b_bc, dt_bias, w_mout, w_out,
        xseqb, winT, wcatT, bcat, wmoT, woT);
    // 2. proj GEMM: xact bf16 | gsil bf16
    gemm_bf16<1><<<dim3(768 / 128, 9216 / 64), 256, 0, stream>>>(
        xseqb, winT, nullptr, nullptr, xact, gsil, DIMC, DIMC, DIMC, 0);
    // 3. zx GEMM: zsil bf16 | xhb bf16 | bcdt fp32(+bias)
    gemm_bf16<2><<<dim3(ZLD / 128, 9216 / 64), 256, 0, stream>>>(
        xact, wcatT, bcat, bcdt, zsil, xhb, EE, EE, EE, 0);
    // 4. dt / r / cumsum (24 blocks — serial dim only)
    k_dtcum<<<NBH, 256, 0, stream>>>(bcdt, A_log, dtv, rrv, cum);
    // 5. rotate B/C (216 blocks — parallel, float4 I/O)
    k_rot<<<(NBH * LL + 255) / 256, 256, 0, stream>>>(bcdt, cum, theta, btct);
    // 6-8. chunked scan (two-pass)
    k_scan_phase<0><<<dim3(NCHUNK, NBH), 64, 0, stream>>>(btct, rrv, dtv, xhb, h0, Hc, Rc, yDb, D_skip);
    k_scan_combine<<<NBH, 64, 0, stream>>>(Hc, Rc, h0);
    k_scan_phase<1><<<dim3(NCHUNK, NBH), 64, 0, stream>>>(btct, rrv, dtv, xhb, h0, Hc, Rc, yDb, D_skip);
    // 9. g = rms(y*zsil)*rms_w -> bf16 (into xact alias); 4 rows/block vectorized
    k_gmul<<<9216 / 4, 256, 0, stream>>>(yDb, zsil, rms_w, g_bf);
    // 10. mres = g @ w_mout -> bf16 (into zsil alias)
    gemm_bf16<3><<<dim3(384 / 128, 9216 / 64), 256, 0, stream>>>(
        g_bf, wmoT, nullptr, nullptr, mresb, nullptr, 384, 384, 384, 384);
    // 11. outT = merge(mres,gsil) @ w_out — merge fused into A-staging
    gemm_out_merge<<<dim3(256 / 128, LL / 64), 256, 0, stream>>>(mresb, gsil, woT, outT);
    // 12. layernorm + residual
    k_ln<<<LL, 64, 0, stream>>>(outT, x, ln_g, ln_b, res_scale, outF);
    (void)in_sizes; (void)n_in; (void)out_size; (void)ws_size;
}

// Round 24
// 157.548 us; speedup vs baseline: 1.0282x; 1.0282x over previous
//
#include <hip/hip_runtime.h>
#include <hip/hip_bf16.h>
#include <math.h>

// ---------------- problem constants ----------------
#define BN   1
#define DIMC 192
#define HI   48
#define WI   48
#define LL   2304          // HI*WI
#define EE   384
#define NN   16
#define PP   64
#define HHH  6
#define HALF 8
#define KK   4
#define BK_SEQ (BN*KK)     // 4
#define NBH  (BK_SEQ*HHH)  // 24
#define CLEN 24
#define NCHUNK 96          // CLEN*NCHUNK == LL
#define ZLD  896           // logical concat width of z|x|bc|dt GEMM (7*128)

typedef __attribute__((ext_vector_type(8))) short bf16x8;
typedef __attribute__((ext_vector_type(4))) float f32x4;

static __device__ __forceinline__ float siluf(float v) {
    return v / (1.f + expf(-v));
}
static __device__ __forceinline__ unsigned short f2bf(float f) {
    unsigned int u = __float_as_uint(f);
    u = (u + 0x7FFFu + ((u >> 16) & 1u)) >> 16;   // RNE
    return (unsigned short)u;
}
static __device__ __forceinline__ float bf2f(unsigned short u) {
    return __uint_as_float((unsigned int)u << 16);
}

// ---------------- fused prep: xseq | winT | wcatT | biascat | wmoT | woT ----------------
#define NP0 (KK*LL*DIMC)        // 1,769,472  xseq bf16
#define NP1 (768*DIMC)          //   147,456  winT bf16  (w_in^T)
#define NP2 (ZLD*EE)            //   344,064  wcatT bf16
#define NP2b 896                //            biascat fp32
#define NP3 (EE*EE)             //   147,456  wmoT bf16  (w_mout^T)
#define NP4 (256*EE)            //    98,304  woT bf16   (w_out^T, N-padded)
#define NPTOT (NP0+NP1+NP2+NP2b+NP3+NP4)

__global__ __launch_bounds__(256) void k_prep_all(const float* __restrict__ x,
                                                  const float* __restrict__ w_in,
                                                  const float* __restrict__ w_zx,
                                                  const float* __restrict__ w_bc,
                                                  const float* __restrict__ w_dt,
                                                  const float* __restrict__ b_bc,
                                                  const float* __restrict__ dt_bias,
                                                  const float* __restrict__ w_mout,
                                                  const float* __restrict__ w_out,
                                                  unsigned short* __restrict__ xseq,
                                                  unsigned short* __restrict__ winT,
                                                  unsigned short* __restrict__ wcatT,
                                                  float* __restrict__ biascat,
                                                  unsigned short* __restrict__ wmoT,
                                                  unsigned short* __restrict__ woT) {
    int idx = blockIdx.x * 256 + threadIdx.x;
    if (idx < NP0) {
        int d = idx % DIMC;
        int l = (idx / DIMC) % LL;
        int k = idx / (DIMC * LL);
        int dim = l / 12;
        int pos = (l % 12) * DIMC + d;
        int src;
        if (k == 0)      src = pos;
        else if (k == 1) src = (pos % 48) * 48 + pos / 48;
        else if (k == 2) src = 2303 - pos;
        else { int p2 = 2303 - pos; src = (p2 % 48) * 48 + p2 / 48; }
        xseq[idx] = f2bf(x[dim * LL + src]);
        return;
    }
    idx -= NP0;
    if (idx < NP1) {            // winT[n*192+k] = w_in[k*768+n]
        int r = idx % DIMC;
        int c = idx / DIMC;
        winT[idx] = f2bf(w_in[(size_t)r * 768 + c]);
        return;
    }
    idx -= NP1;
    if (idx < NP2) {            // wcatT[n*384+k] = [w_zx|w_bc|w_dt][k][n]
        int n = idx / EE, k = idx % EE;
        float v = 0.f;
        if (n < 768)      v = w_zx[(size_t)k * 768 + n];
        else if (n < 800) v = w_bc[(size_t)k * 32 + (n - 768)];
        else if (n < 806) v = w_dt[(size_t)k * 6 + (n - 800)];
        wcatT[idx] = f2bf(v);
        return;
    }
    idx -= NP2;
    if (idx < NP2b) {           // biascat fp32
        float v = 0.f;
        if (idx >= 768 && idx < 800) v = b_bc[idx - 768];
        else if (idx >= 800 && idx < 806) v = dt_bias[idx - 800];
        biascat[idx] = v;
        return;
    }
    idx -= NP2b;
    if (idx < NP3) {            // wmoT[n*384+k] = w_mout[k*384+n]
        int r = idx % EE;
        int c = idx / EE;
        wmoT[idx] = f2bf(w_mout[(size_t)r * EE + c]);
        return;
    }
    idx -= NP3;
    if (idx < NP4) {            // woT[d*384+e] = d<192 ? w_out[e*192+d] : 0
        int d = idx / EE, e = idx % EE;
        woT[idx] = (d < DIMC) ? f2bf(w_out[(size_t)e * DIMC + d]) : (unsigned short)0;
    }
}

// ---------------- bf16 MFMA GEMM: out = A * BT^T ----------------
// Tile 64(M) x 128(N), BK=32, 4 waves, single barrier/iter, LDS dbuf.
// EPI=0: C fp32 (+bias), ld ldc.                      [out GEMM]
// EPI=1: col<384 -> X bf16 silu; col>=384 -> Y bf16 silu (gate).   [proj]
// EPI=2: col<384 -> X bf16 silu (zsil); 384<=col<768 -> Y bf16 (xh);
//        col>=768 -> C fp32 ld 128 at col-768, + bias[col].        [zx]
// EPI=3: X bf16, ld ldc (no bias).                    [mout]
template <int EPI>
__global__ __launch_bounds__(256) void gemm_bf16(const unsigned short* __restrict__ A,
                                                 const unsigned short* __restrict__ BT,
                                                 const float* __restrict__ bias,
                                                 float* __restrict__ C,
                                                 unsigned short* __restrict__ X,
                                                 unsigned short* __restrict__ Y,
                                                 int K, int lda, int ldbt, int ldc) {
    __shared__ __align__(16) unsigned short As[2][64][40];
    __shared__ __align__(16) unsigned short Bs[2][128][40];
    int bm = blockIdx.y * 64, bn = blockIdx.x * 128;
    int tid = threadIdx.x;
    int lane = tid & 63, wave = tid >> 6;
    int wn = wave * 32;
    f32x4 acc[4][2];
#pragma unroll
    for (int f = 0; f < 4; f++)
#pragma unroll
        for (int g = 0; g < 2; g++) acc[f][g] = (f32x4){0.f, 0.f, 0.f, 0.f};

    int fr = lane & 15;
    int kl = (lane >> 4) * 8;

    int sr = tid >> 2;
    int sq = (tid & 3) * 8;
    const unsigned short* aptr  = A + (size_t)(bm + sr) * lda + sq;
    const unsigned short* bptr0 = BT + (size_t)(bn + sr) * ldbt + sq;
    const unsigned short* bptr1 = BT + (size_t)(bn + sr + 64) * ldbt + sq;

    uint4 pa  = *(const uint4*)aptr;
    uint4 pb0 = *(const uint4*)bptr0;
    uint4 pb1 = *(const uint4*)bptr1;
    *(uint4*)&As[0][sr][sq]      = pa;
    *(uint4*)&Bs[0][sr][sq]      = pb0;
    *(uint4*)&Bs[0][sr + 64][sq] = pb1;
    if (K > 32) {
        pa  = *(const uint4*)(aptr + 32);
        pb0 = *(const uint4*)(bptr0 + 32);
        pb1 = *(const uint4*)(bptr1 + 32);
    }
    __syncthreads();

    for (int k0 = 0; k0 < K; k0 += 32) {
        int cur = (k0 >> 5) & 1;
        bf16x8 af[4], bg[2];
#pragma unroll
        for (int f = 0; f < 4; f++) af[f] = *(const bf16x8*)&As[cur][f * 16 + fr][kl];
#pragma unroll
        for (int g = 0; g < 2; g++) bg[g] = *(const bf16x8*)&Bs[cur][wn + g * 16 + fr][kl];
        if (k0 + 32 < K) {
            *(uint4*)&As[cur ^ 1][sr][sq]      = pa;
            *(uint4*)&Bs[cur ^ 1][sr][sq]      = pb0;
            *(uint4*)&Bs[cur ^ 1][sr + 64][sq] = pb1;
        }
        if (k0 + 64 < K) {
            pa  = *(const uint4*)(aptr + k0 + 64);
            pb0 = *(const uint4*)(bptr0 + k0 + 64);
            pb1 = *(const uint4*)(bptr1 + k0 + 64);
        }
        __syncthreads();
#pragma unroll
        for (int f = 0; f < 4; f++)
#pragma unroll
            for (int g = 0; g < 2; g++)
                acc[f][g] = __builtin_amdgcn_mfma_f32_16x16x32_bf16(af[f], bg[g], acc[f][g], 0, 0, 0);
    }
    int cc = lane & 15, crb = (lane >> 4) * 4;
#pragma unroll
    for (int f = 0; f < 4; f++)
#pragma unroll
        for (int g = 0; g < 2; g++) {
            int col = bn + wn + g * 16 + cc;
            int rowb = bm + f * 16 + crb;
            if (EPI == 0) {
                float bv = bias ? bias[col] : 0.f;
#pragma unroll
                for (int i = 0; i < 4; i++)
                    C[(size_t)(rowb + i) * ldc + col] = acc[f][g][i] + bv;
            } else if (EPI == 1) {
                if (col < 384) {
#pragma unroll
                    for (int i = 0; i < 4; i++)
                        X[(size_t)(rowb + i) * 384 + col] = f2bf(siluf(acc[f][g][i]));
                } else {
#pragma unroll
                    for (int i = 0; i < 4; i++)
                        Y[(size_t)(rowb + i) * 384 + col - 384] = f2bf(siluf(acc[f][g][i]));
                }
            } else if (EPI == 2) {
                if (col < 384) {
#pragma unroll
                    for (int i = 0; i < 4; i++)
                        X[(size_t)(rowb + i) * 384 + col] = f2bf(siluf(acc[f][g][i]));
                } else if (col < 768) {
#pragma unroll
                    for (int i = 0; i < 4; i++)
                        Y[(size_t)(rowb + i) * 384 + col - 384] = f2bf(acc[f][g][i]);
                } else {
                    float bv = bias[col];
#pragma unroll
                    for (int i = 0; i < 4; i++)
                        C[(size_t)(rowb + i) * 128 + col - 768] = acc[f][g][i] + bv;
                }
            } else {  // EPI == 3
#pragma unroll
                for (int i = 0; i < 4; i++)
                    X[(size_t)(rowb + i) * ldc + col] = f2bf(acc[f][g][i]);
            }
        }
}

// ---------------- softplus/r + cumsum of dt over l, per (bh); reads bcdt ----------------
__global__ __launch_bounds__(256) void k_dtcum(const float* __restrict__ bcdt,
                                               const float* __restrict__ A_log,
                                               float* __restrict__ dtv,
                                               float* __restrict__ rrv,
                                               float* __restrict__ cum) {
    int bh = blockIdx.x;
    int tid = threadIdx.x;
    int b = bh / HHH, h = bh % HHH;
    float aexp = expf(A_log[h]);
    const int PER = 9;                    // 256*9 = 2304
    int base = tid * PER;
    float p[PER];
    float s = 0.f;
#pragma unroll
    for (int j = 0; j < PER; j++) {
        int l = base + j;
        float xv = bcdt[((size_t)b * LL + l) * 128 + 32 + h];
        float sp = fmaxf(xv, 0.f) + log1pf(expf(-fabsf(xv)));   // softplus
        dtv[(size_t)bh * LL + l] = sp;
        rrv[(size_t)bh * LL + l] = expf(-sp * aexp);
        s += sp; p[j] = s;
    }
    __shared__ float sh[256];
    sh[tid] = s;
    __syncthreads();
    for (int off = 1; off < 256; off <<= 1) {
        float t = (tid >= off) ? sh[tid - off] : 0.f;
        __syncthreads();
        sh[tid] += t;
        __syncthreads();
    }
    float excl = sh[tid] - s;
#pragma unroll
    for (int j = 0; j < PER; j++) cum[(size_t)bh * LL + base + j] = excl + p[j];
}

// ---- RMS-normalize B/C and rotate -> btct; one thread per (b,h,l); float4 I/O ----
__global__ __launch_bounds__(256) void k_rot(const float* __restrict__ bcdt,
                                             const float* __restrict__ cum,
                                             const float* __restrict__ theta,
                                             float* __restrict__ btct) {
    int idx = blockIdx.x * 256 + threadIdx.x;
    if (idx >= NBH * LL) return;
    int bh = idx / LL, l = idx % LL;
    int b = bh / HHH, h = bh % HHH;
    const float4* bcrow = (const float4*)(bcdt + ((size_t)b * LL + l) * 128);
    float Bm[16], Cm[16];
#pragma unroll
    for (int q = 0; q < 4; q++) {
        *(float4*)&Bm[q * 4] = bcrow[q];
        *(float4*)&Cm[q * 4] = bcrow[4 + q];
    }
    float sb = 0.f, sc = 0.f;
#pragma unroll
    for (int j = 0; j < 16; j++) { sb += Bm[j] * Bm[j]; sc += Cm[j] * Cm[j]; }
    float rb = rsqrtf(sb * (1.f / 16.f) + 1e-6f);
    float rc = rsqrtf(sc * (1.f / 16.f) + 1e-6f);
    float cd = cum[(size_t)bh * LL + l];
    float out32[32];
#pragma unroll
    for (int j = 0; j < 8; j++) {
        float ang = cd * theta[h * 8 + j];
        float cc = cosf(ang), ss = sinf(ang);
        float b0 = Bm[2 * j] * rb, b1 = Bm[2 * j + 1] * rb;
        out32[2 * j]     = b0 * cc + b1 * ss;
        out32[2 * j + 1] = -b0 * ss + b1 * cc;
        float c0 = Cm[2 * j] * rc, c1 = Cm[2 * j + 1] * rc;
        out32[16 + 2 * j]     = c0 * cc + c1 * ss;
        out32[16 + 2 * j + 1] = -c0 * ss + c1 * cc;
    }
    float4* outp = (float4*)(btct + ((size_t)bh * LL + l) * 32);
#pragma unroll
    for (int q = 0; q < 8; q++) outp[q] = *(const float4*)&out32[q * 4];
}

// ---------------- scan phases A (MODE 0) and C (MODE 1), two-pass ----------------
template <int MODE>
__global__ __launch_bounds__(64) void k_scan_phase(const float* __restrict__ btct,
                                                   const float* __restrict__ rrv,
                                                   const float* __restrict__ dtv,
                                                   const unsigned short* __restrict__ xhb,
                                                   const float* __restrict__ h0,
                                                   float* __restrict__ Hc,
                                                   float* __restrict__ Rc,
                                                   unsigned short* __restrict__ yDb,
                                                   const float* __restrict__ Dsk) {
    int chunk = blockIdx.x;
    int bh = blockIdx.y;
    int lane = threadIdx.x;
    int b = bh / HHH, h = bh % HHH;
    int t0 = chunk * CLEN;

    __shared__ float sbt[(CLEN + 1) * 32];
    __shared__ float srd[2 * CLEN];

    const float* bt_row = btct + (size_t)bh * LL * 32;
    for (int i = lane; i < (CLEN + 1) * 8; i += 64) {
        int t = t0 - 1 + (i >> 3);
        float4 v = make_float4(0.f, 0.f, 0.f, 0.f);
        if (t >= 0)
            v = ((const float4*)(bt_row + (size_t)t * 32))[i & 7];
        ((float4*)sbt)[i] = v;
    }
    if (lane < CLEN) {
        srd[lane] = rrv[(size_t)bh * LL + t0 + lane];
        srd[CLEN + lane] = 0.5f * dtv[(size_t)bh * LL + t0 + lane];
    }

    const unsigned short* xcol = xhb + (size_t)b * LL * EE + h * PP + lane;
    float xr[CLEN];
#pragma unroll
    for (int j = 0; j < CLEN; j++) xr[j] = bf2f(xcol[(size_t)(t0 + j) * EE]);
    float xprev = (t0 > 0) ? bf2f(xcol[(size_t)(t0 - 1) * EE]) : 0.f;

    float hreg[16];
    if (MODE == 0) {
#pragma unroll
        for (int n = 0; n < 16; n++) hreg[n] = 0.f;
    } else {
        const float* hp = h0 + ((size_t)(chunk * NBH + bh) * 16) * PP + lane;
#pragma unroll
        for (int n = 0; n < 16; n++) hreg[n] = hp[n * PP];
    }
    float dsk = (MODE == 1) ? Dsk[h] : 0.f;
    __syncthreads();

    float Btp[16];
#pragma unroll
    for (int n = 0; n < 16; n++) Btp[n] = sbt[n];
    float Rprod = 1.f;

#pragma unroll
    for (int j = 0; j < CLEN; j++) {
        float r = srd[j];
        float dhalf = srd[CLEN + j];
        float xcur = xr[j];
        const float* bb = sbt + (j + 1) * 32;
        float a = dhalf * xcur;
        float ap = dhalf * r * xprev;
        float y = 0.f;
#pragma unroll
        for (int n = 0; n < 16; n++) {
            float Btn = bb[n];
            hreg[n] = r * hreg[n] + a * Btn + ap * Btp[n];
            Btp[n] = Btn;
            if (MODE) y += bb[16 + n] * hreg[n];
        }
        xprev = xcur;
        if (MODE) {
            yDb[((size_t)b * LL + t0 + j) * EE + h * PP + lane] = f2bf(y + dsk * xcur);
        } else {
            Rprod *= r;
        }
    }
    if (MODE == 0) {
        float* Hp = Hc + ((size_t)(chunk * NBH + bh) * 16) * PP + lane;
#pragma unroll
        for (int n = 0; n < 16; n++) Hp[n * PP] = hreg[n];
        if (lane == 0) Rc[chunk * NBH + bh] = Rprod;
    }
}

// ---------------- scan phase B: combine chunk summaries ----------------
__global__ __launch_bounds__(64) void k_scan_combine(const float* __restrict__ Hc,
                                                     const float* __restrict__ Rc,
                                                     float* __restrict__ h0) {
    int bh = blockIdx.x;
    int lane = threadIdx.x;
    float s[16];
#pragma unroll
    for (int n = 0; n < 16; n++) s[n] = 0.f;
    float* out0 = h0 + ((size_t)(0 * NBH + bh) * 16) * PP + lane;
#pragma unroll
    for (int n = 0; n < 16; n++) out0[n * PP] = 0.f;
    for (int c = 0; c < NCHUNK - 1; ++c) {
        float R = Rc[c * NBH + bh];
        const float* Hp = Hc + ((size_t)(c * NBH + bh) * 16) * PP + lane;
        float* op = h0 + ((size_t)((c + 1) * NBH + bh) * 16) * PP + lane;
#pragma unroll
        for (int n = 0; n < 16; n++) {
            s[n] = R * s[n] + Hp[n * PP];
            op[n * PP] = s[n];
        }
    }
}

// ---- g = rms(y * zsil) * rms_w; 4 rows/block, 1 wave/row, uint4 (8 bf16)/lane ----
__global__ __launch_bounds__(256) void k_gmul(const unsigned short* __restrict__ yDb,
                                              const unsigned short* __restrict__ zsil,
                                              const float* __restrict__ rms_w,
                                              unsigned short* __restrict__ g) {
    int wid = threadIdx.x >> 6, lane = threadIdx.x & 63;
    int row = blockIdx.x * 4 + wid;
    float v[8];
    float ss = 0.f;
    if (lane < 48) {
        uint4 yv = *(const uint4*)&yDb[(size_t)row * EE + lane * 8];
        uint4 zv = *(const uint4*)&zsil[(size_t)row * EE + lane * 8];
        const unsigned short* yp = (const unsigned short*)&yv;
        const unsigned short* zp = (const unsigned short*)&zv;
#pragma unroll
        for (int j = 0; j < 8; j++) {
            v[j] = bf2f(yp[j]) * bf2f(zp[j]);
            ss += v[j] * v[j];
        }
    }
#pragma unroll
    for (int off = 1; off < 64; off <<= 1) ss += __shfl_xor(ss, off);
    float scale = rsqrtf(ss * (1.f / (float)EE) + 1e-6f);
    if (lane < 48) {
        unsigned short o[8];
#pragma unroll
        for (int j = 0; j < 8; j++)
            o[j] = f2bf(v[j] * scale * rms_w[lane * 8 + j]);
        *(uint4*)&g[(size_t)row * EE + lane * 8] = *(const uint4*)o;
    }
}

// ---- gate + 4-direction merge -> mrg bf16; 8 e per thread (uint4) ----
__global__ __launch_bounds__(256) void k_merge(const unsigned short* __restrict__ mresb,
                                               const unsigned short* __restrict__ gsil,
                                               unsigned short* __restrict__ mrg) {
    int idx = blockIdx.x * 256 + threadIdx.x;
    if (idx >= LL * EE / 8) return;
    int e = (idx % (EE / 8)) * 8;
    int l = idx / (EE / 8);
    int l1 = (l % 48) * 48 + l / 48;
    int rows[4];
    rows[0] = 0 * LL + l;
    rows[1] = 1 * LL + l1;
    rows[2] = 2 * LL + (2303 - l);
    rows[3] = 3 * LL + (2303 - l1);
    float acc[8];
#pragma unroll
    for (int j = 0; j < 8; j++) acc[j] = 0.f;
#pragma unroll
    for (int k = 0; k < 4; k++) {
        uint4 mv = *(const uint4*)&mresb[(size_t)rows[k] * EE + e];
        uint4 gv = *(const uint4*)&gsil[(size_t)rows[k] * EE + e];
        const unsigned short* mp = (const unsigned short*)&mv;
        const unsigned short* gp = (const unsigned short*)&gv;
#pragma unroll
        for (int j = 0; j < 8; j++) acc[j] += bf2f(mp[j]) * bf2f(gp[j]);
    }
    unsigned short o[8];
#pragma unroll
    for (int j = 0; j < 8; j++) o[j] = f2bf(acc[j]);
    *(uint4*)&mrg[(size_t)l * EE + e] = *(const uint4*)o;
}

// ---------------- LayerNorm over channels + residual ----------------
__global__ __launch_bounds__(64) void k_ln(const float* __restrict__ outT,
                                           const float* __restrict__ x,
                                           const float* __restrict__ ln_g,
                                           const float* __restrict__ ln_b,
                                           const float* __restrict__ res_scale,
                                           float* __restrict__ outF) {
    int l = blockIdx.x;
    int lane = threadIdx.x;
    float v[3];
    float s = 0.f;
#pragma unroll
    for (int j = 0; j < 3; j++) {
        int d = lane * 3 + j;
        v[j] = outT[(size_t)l * 256 + d];
        s += v[j];
    }
#pragma unroll
    for (int off = 1; off < 64; off <<= 1) s += __shfl_xor(s, off);
    float mu = s * (1.f / (float)DIMC);
    float sq = 0.f;
#pragma unroll
    for (int j = 0; j < 3; j++) { float dlt = v[j] - mu; sq += dlt * dlt; }
#pragma unroll
    for (int off = 1; off < 64; off <<= 1) sq += __shfl_xor(sq, off);
    float rstd = rsqrtf(sq * (1.f / (float)DIMC) + 1e-5f);
    float rs = res_scale[0];
#pragma unroll
    for (int j = 0; j < 3; j++) {
        int d = lane * 3 + j;
        outF[(size_t)d * LL + l] =
            x[(size_t)d * LL + l] + rs * ((v[j] - mu) * rstd * ln_g[d] + ln_b[d]);
    }
}

// ---------------- host launcher ----------------
extern "C" void kernel_launch(void* const* d_in, const int* in_sizes, int n_in,
                              void* d_out, int out_size, void* d_ws, size_t ws_size,
                              hipStream_t stream) {
    const float* x        = (const float*)d_in[0];
    const float* w_in     = (const float*)d_in[1];
    const float* w_zx     = (const float*)d_in[2];
    const float* w_bc     = (const float*)d_in[3];
    const float* b_bc     = (const float*)d_in[4];
    const float* w_dt     = (const float*)d_in[5];
    const float* dt_bias  = (const float*)d_in[6];
    const float* A_log    = (const float*)d_in[7];
    const float* theta    = (const float*)d_in[8];
    const float* D_skip   = (const float*)d_in[9];
    const float* rms_w    = (const float*)d_in[10];
    const float* w_mout   = (const float*)d_in[11];
    const float* w_out    = (const float*)d_in[12];
    const float* ln_g     = (const float*)d_in[13];
    const float* ln_b     = (const float*)d_in[14];
    const float* res_scale= (const float*)d_in[15];
    float* outF = (float*)d_out;
    float* ws = (float*)d_ws;

    size_t o = 0;
    auto alloc = [&](size_t n) { size_t r = o; o += (n + 127) & ~(size_t)127; return r; };
    size_t xseqb_o = alloc((size_t)9216 * DIMC / 2);   // bf16
    size_t winT_o  = alloc((size_t)768 * DIMC / 2);    // bf16
    size_t wcatT_o = alloc((size_t)ZLD * EE / 2);      // bf16
    size_t wmoT_o  = alloc((size_t)384 * 384 / 2);     // bf16
    size_t woT_o   = alloc((size_t)256 * EE / 2);      // bf16
    size_t bcat_o  = alloc(ZLD);
    size_t xact_o  = alloc((size_t)9216 * EE / 2);     // bf16; reused as g_bf
    size_t gsil_o  = alloc((size_t)9216 * EE / 2);     // bf16 silu(gate)
    size_t zsil_o  = alloc((size_t)9216 * EE / 2);     // bf16 silu(z); reused as mresb
    size_t xhb_o   = alloc((size_t)9216 * EE / 2);     // bf16 xi
    size_t bcdt_o  = alloc((size_t)9216 * 128);        // fp32 bc|dt
    size_t dtv_o   = alloc((size_t)NBH * LL);
    size_t rrv_o   = alloc((size_t)NBH * LL);
    size_t cum_o   = alloc((size_t)NBH * LL);
    size_t btct_o  = alloc((size_t)NBH * LL * 32);
    size_t Hc_o    = alloc((size_t)NCHUNK * NBH * 16 * PP);
    size_t Rc_o    = alloc((size_t)NCHUNK * NBH);
    size_t h0_o    = alloc((size_t)NCHUNK * NBH * 16 * PP);
    size_t yDb_o   = alloc((size_t)9216 * EE / 2);     // bf16
    size_t mrg_o   = alloc((size_t)LL * EE / 2);       // bf16
    size_t outT_o  = alloc((size_t)LL * 256);

    unsigned short* xseqb = (unsigned short*)(ws + xseqb_o);
    unsigned short* winT  = (unsigned short*)(ws + winT_o);
    unsigned short* wcatT = (unsigned short*)(ws + wcatT_o);
    unsigned short* wmoT  = (unsigned short*)(ws + wmoT_o);
    unsigned short* woT   = (unsigned short*)(ws + woT_o);
    float* bcat = ws + bcat_o;
    unsigned short* xact = (unsigned short*)(ws + xact_o);
    unsigned short* gsil = (unsigned short*)(ws + gsil_o);
    unsigned short* zsil = (unsigned short*)(ws + zsil_o);
    unsigned short* xhb  = (unsigned short*)(ws + xhb_o);
    float* bcdt = ws + bcdt_o;
    float* dtv  = ws + dtv_o;
    float* rrv  = ws + rrv_o;
    float* cum  = ws + cum_o;
    float* btct = ws + btct_o;
    float* Hc   = ws + Hc_o;
    float* Rc   = ws + Rc_o;
    float* h0   = ws + h0_o;
    unsigned short* yDb = (unsigned short*)(ws + yDb_o);
    unsigned short* mrg = (unsigned short*)(ws + mrg_o);
    float* outT = ws + outT_o;
    unsigned short* g_bf  = xact;   // alias (xact dead after zx GEMM)
    unsigned short* mresb = zsil;   // alias (zsil dead after k_gmul)

    // 1. fused prep
    k_prep_all<<<(NPTOT + 255) / 256, 256, 0, stream>>>(
        x, w_in, w_zx, w_bc, w_dt, b_bc, dt_bias, w_mout, w_out,
        xseqb, winT, wcatT, bcat, wmoT, woT);
    // 2. proj GEMM: xact bf16 | gsil bf16
    gemm_bf16<1><<<dim3(768 / 128, 9216 / 64), 256, 0, stream>>>(
        xseqb, winT, nullptr, nullptr, xact, gsil, DIMC, DIMC, DIMC, 0);
    // 3. zx GEMM: zsil bf16 | xhb bf16 | bcdt fp32(+bias)
    gemm_bf16<2><<<dim3(ZLD / 128, 9216 / 64), 256, 0, stream>>>(
        xact, wcatT, bcat, bcdt, zsil, xhb, EE, EE, EE, 0);
    // 4. dt / r / cumsum (24 blocks — serial dim only)
    k_dtcum<<<NBH, 256, 0, stream>>>(bcdt, A_log, dtv, rrv, cum);
    // 5. rotate B/C (216 blocks — parallel, float4 I/O)
    k_rot<<<(NBH * LL + 255) / 256, 256, 0, stream>>>(bcdt, cum, theta, btct);
    // 6-8. chunked scan (two-pass)
    k_scan_phase<0><<<dim3(NCHUNK, NBH), 64, 0, stream>>>(btct, rrv, dtv, xhb, h0, Hc, Rc, yDb, D_skip);
    k_scan_combine<<<NBH, 64, 0, stream>>>(Hc, Rc, h0);
    k_scan_phase<1><<<dim3(NCHUNK, NBH), 64, 0, stream>>>(btct, rrv, dtv, xhb, h0, Hc, Rc, yDb, D_skip);
    // 9. g = rms(y*zsil)*rms_w -> bf16 (into xact alias); 4 rows/block vectorized
    k_gmul<<<9216 / 4, 256, 0, stream>>>(yDb, zsil, rms_w, g_bf);
    // 10. mres = g @ w_mout -> bf16 (into zsil alias)
    gemm_bf16<3><<<dim3(384 / 128, 9216 / 64), 256, 0, stream>>>(
        g_bf, wmoT, nullptr, nullptr, mresb, nullptr, 384, 384, 384, 384);
    // 11. gate + merge -> mrg bf16 (8 e/thread vectorized)
    k_merge<<<(LL * EE / 8 + 255) / 256, 256, 0, stream>>>(mresb, gsil, mrg);
    // 12. outT = mrg @ w_out (2304 x 256(pad 192) x 384) fp32
    gemm_bf16<0><<<dim3(256 / 128, LL / 64), 256, 0, stream>>>(
        mrg, woT, nullptr, outT, nullptr, nullptr, EE, EE, EE, 256);
    // 13. layernorm + residual
    k_ln<<<LL, 64, 0, stream>>>(outT, x, ln_g, ln_b, res_scale, outF);
    (void)in_sizes; (void)n_in; (void)out_size; (void)ws_size;
}